// Round 1
// baseline (5428.892 us; speedup 1.0000x reference)
//
#include <hip/hip_runtime.h>
#include <hip/hip_bf16.h>

typedef unsigned short u16;
typedef unsigned int u32;
typedef __attribute__((ext_vector_type(8))) short short8;
typedef __attribute__((ext_vector_type(4))) float f32x4;

#define GLD_LDS(gptr, lptr) \
    __builtin_amdgcn_global_load_lds((const __attribute__((address_space(1))) void*)(gptr), \
                                     (__attribute__((address_space(3))) void*)(lptr), 16, 0, 0)

__device__ __forceinline__ u32 bf16_rne(float f) {
    u32 u = __float_as_uint(f);
    return (u + 0x7FFFu + ((u >> 16) & 1u)) >> 16;
}

// ---------------------------------------------------------------------------
// Transpose + split fp32 [1024][N] -> bf16 hi/lo [N][1024]
// ---------------------------------------------------------------------------
__global__ __launch_bounds__(256) void transpose_split(
    const float* __restrict__ W, u16* __restrict__ Thi, u16* __restrict__ Tlo, int N)
{
    __shared__ float tile[64][65];
    int n0 = blockIdx.x * 64;
    int k0 = blockIdx.y * 64;
    int tid = threadIdx.x;
    int tr = tid >> 4;      // 0..15
    int tc = tid & 15;      // 0..15
#pragma unroll
    for (int it = 0; it < 4; ++it) {
        int kr = it * 16 + tr;
        const float4* src = (const float4*)&W[(size_t)(k0 + kr) * N + n0 + tc * 4];
        float4 v = *src;
        tile[kr][tc * 4 + 0] = v.x;
        tile[kr][tc * 4 + 1] = v.y;
        tile[kr][tc * 4 + 2] = v.z;
        tile[kr][tc * 4 + 3] = v.w;
    }
    __syncthreads();
#pragma unroll
    for (int it = 0; it < 4; ++it) {
        int nr = it * 16 + tr;
        u32 h[4], l[4];
#pragma unroll
        for (int j = 0; j < 4; ++j) {
            float f = tile[tc * 4 + j][nr];
            u32 hi = bf16_rne(f);
            float hif = __uint_as_float(hi << 16);
            float lo = f - hif;
            h[j] = hi;
            l[j] = bf16_rne(lo);
        }
        size_t idx = (size_t)(n0 + nr) * 1024 + k0 + tc * 4;
        uint2 ph, pl;
        ph.x = h[0] | (h[1] << 16); ph.y = h[2] | (h[3] << 16);
        pl.x = l[0] | (l[1] << 16); pl.y = l[2] | (l[3] << 16);
        *(uint2*)&Thi[idx] = ph;
        *(uint2*)&Tlo[idx] = pl;
    }
}

// ---------------------------------------------------------------------------
// Init: zero c, zero h splits, bias_sum = bi + bh
// ---------------------------------------------------------------------------
__global__ __launch_bounds__(256) void init_state(
    float* __restrict__ c, u16* __restrict__ hh, u16* __restrict__ hl,
    float* __restrict__ bsum, const float* __restrict__ bi, const float* __restrict__ bh)
{
    int i = blockIdx.x * 256 + threadIdx.x;   // 0 .. 1048575
    c[i] = 0.0f;
    if (i < 262144) { hh[i] = 0; hl[i] = 0; }
    if (i < 16384)  bsum[i] = bi[i] + bh[i];
}

// ---------------------------------------------------------------------------
// bf16x3 GEMM: C[256][N] = h(256x1024) @ W(1024xN) (+ bias [+ Wi[X[:,t]] gather])
// A given as bf16 hi/lo [256][1024]; B given transposed bf16 hi/lo [N][1024].
// BM=128, BN=64, BK=32; 256 threads (4 waves); wave = 64 rows x 32 cols.
// EPI==0: gates epilogue (bias_sum + Wi gather). EPI==1: logits (bias=bl).
// ---------------------------------------------------------------------------
template <int EPI>
__global__ __launch_bounds__(256, 2) void gemm3(
    const u16* __restrict__ Ahi, const u16* __restrict__ Alo,
    const u16* __restrict__ Bhi, const u16* __restrict__ Blo,
    float* __restrict__ C, int N,
    const float* __restrict__ bias,
    const int* __restrict__ X, int t, const float* __restrict__ Wi)
{
    constexpr int KD = 1024;
    // LDS layout (ushorts): AHI [0,4096), ALO [4096,8192), BHI [8192,10240), BLO [10240,12288)
    __shared__ u16 lds[2][12288];

    int bid  = blockIdx.x;
    int m0   = (bid & 1) * 128;
    int n0   = (bid >> 1) * 64;
    int tid  = threadIdx.x;
    int lane = tid & 63;
    int wave = tid >> 6;
    int wm = wave >> 1, wn = wave & 1;
    int quad = lane >> 4, l15 = lane & 15;

    f32x4 acc[4][2] = {};

    auto stage = [&](int buf, int kc) {
        int k0 = kc * 32;
        // A: 128 rows x 4 segs = 512 lane-loads (2 per thread per array)
#pragma unroll
        for (int j = 0; j < 2; ++j) {
            int seg = j * 256 + tid;
            int row = seg >> 2, s = seg & 3;
            size_t go = (size_t)(m0 + row) * KD + k0 + s * 8;
            GLD_LDS(Ahi + go, &lds[buf][0    + seg * 8]);
            GLD_LDS(Alo + go, &lds[buf][4096 + seg * 8]);
        }
        // B: 64 rows x 4 segs = 256 lane-loads (1 per thread per array)
        {
            int row = tid >> 2, s = tid & 3;
            size_t go = (size_t)(n0 + row) * KD + k0 + s * 8;
            GLD_LDS(Bhi + go, &lds[buf][8192  + tid * 8]);
            GLD_LDS(Blo + go, &lds[buf][10240 + tid * 8]);
        }
    };

    stage(0, 0);
    constexpr int NK = KD / 32;  // 32 chunks
    for (int kc = 0; kc < NK; ++kc) {
        __syncthreads();
        if (kc + 1 < NK) stage((kc + 1) & 1, kc + 1);
        int buf = kc & 1;

        short8 afh[4], afl[4], bfh[2], bfl[2];
#pragma unroll
        for (int mi = 0; mi < 4; ++mi) {
            int row = wm * 64 + mi * 16 + l15;
            afh[mi] = *(const short8*)&lds[buf][0    + row * 32 + quad * 8];
            afl[mi] = *(const short8*)&lds[buf][4096 + row * 32 + quad * 8];
        }
#pragma unroll
        for (int ni = 0; ni < 2; ++ni) {
            int row = wn * 32 + ni * 16 + l15;
            bfh[ni] = *(const short8*)&lds[buf][8192  + row * 32 + quad * 8];
            bfl[ni] = *(const short8*)&lds[buf][10240 + row * 32 + quad * 8];
        }
#pragma unroll
        for (int mi = 0; mi < 4; ++mi)
#pragma unroll
            for (int ni = 0; ni < 2; ++ni) {
                acc[mi][ni] = __builtin_amdgcn_mfma_f32_16x16x32_bf16(afh[mi], bfh[ni], acc[mi][ni], 0, 0, 0);
                acc[mi][ni] = __builtin_amdgcn_mfma_f32_16x16x32_bf16(afh[mi], bfl[ni], acc[mi][ni], 0, 0, 0);
                acc[mi][ni] = __builtin_amdgcn_mfma_f32_16x16x32_bf16(afl[mi], bfh[ni], acc[mi][ni], 0, 0, 0);
            }
    }

    // Epilogue: C/D layout col = lane&15, row = quad*4 + r
#pragma unroll
    for (int mi = 0; mi < 4; ++mi) {
        int rbase = m0 + wm * 64 + mi * 16 + quad * 4;
#pragma unroll
        for (int ni = 0; ni < 2; ++ni) {
            int col = n0 + wn * 32 + ni * 16 + l15;
            float bv = bias[col];
#pragma unroll
            for (int r = 0; r < 4; ++r) {
                int row = rbase + r;
                float v = acc[mi][ni][r] + bv;
                if constexpr (EPI == 0) {
                    int xr = X[row * 128 + t];
                    v += Wi[(size_t)xr * 16384 + col];
                }
                C[(size_t)row * N + col] = v;
            }
        }
    }
}

// ---------------------------------------------------------------------------
// Cell update: gates[256][16384] -> c, h (split to bf16 hi/lo)
// gate index = kk*4096 + gate*1024 + hx ; c index = b*4096 + kk*1024 + hx
// ---------------------------------------------------------------------------
__global__ __launch_bounds__(256) void cell_update(
    const float* __restrict__ gates, float* __restrict__ c,
    u16* __restrict__ hh, u16* __restrict__ hl)
{
    int gid = blockIdx.x * 256 + threadIdx.x;   // 0..262143
    int b = gid >> 10, hx = gid & 1023;
    size_t gb = (size_t)b * 16384 + hx;
    size_t cb = (size_t)b * 4096 + hx;

    float best = -3.4e38f, csel = 0.0f;
#pragma unroll
    for (int kk = 0; kk < 4; ++kk) {
        float gi = gates[gb + kk * 4096 + 0];
        float gf = gates[gb + kk * 4096 + 1024];
        float gg = gates[gb + kk * 4096 + 2048];
        float go = gates[gb + kk * 4096 + 3072];
        float ig = 1.0f / (1.0f + expf(-gi));
        float fg = 1.0f / (1.0f + expf(-gf));
        float tg = tanhf(gg);
        float cn = fg * c[cb + kk * 1024] + ig * tg;
        c[cb + kk * 1024] = cn;
        if (go > best) { best = go; csel = cn; }   // strict > keeps first max (jnp.argmax)
    }
    float h = (1.0f / (1.0f + expf(-best))) * tanhf(csel);
    u32 hi = bf16_rne(h);
    float hif = __uint_as_float(hi << 16);
    u32 lo = bf16_rne(h - hif);
    hh[gid] = (u16)hi;
    hl[gid] = (u16)lo;
}

// ---------------------------------------------------------------------------
// Row-wise log_softmax in place over [256][1024]
// ---------------------------------------------------------------------------
__global__ __launch_bounds__(256) void logsoftmax_k(float* __restrict__ io)
{
    int b = blockIdx.x;
    float* row = io + (size_t)b * 1024;
    int tid = threadIdx.x;
    float x0 = row[tid], x1 = row[tid + 256], x2 = row[tid + 512], x3 = row[tid + 768];
    float m = fmaxf(fmaxf(x0, x1), fmaxf(x2, x3));
#pragma unroll
    for (int off = 32; off > 0; off >>= 1) m = fmaxf(m, __shfl_down(m, off, 64));
    __shared__ float sm[4], ss[4];
    if ((tid & 63) == 0) sm[tid >> 6] = m;
    __syncthreads();
    float M = fmaxf(fmaxf(sm[0], sm[1]), fmaxf(sm[2], sm[3]));
    float s = expf(x0 - M) + expf(x1 - M) + expf(x2 - M) + expf(x3 - M);
#pragma unroll
    for (int off = 32; off > 0; off >>= 1) s += __shfl_down(s, off, 64);
    if ((tid & 63) == 0) ss[tid >> 6] = s;
    __syncthreads();
    float L = M + logf(ss[0] + ss[1] + ss[2] + ss[3]);
    row[tid] = x0 - L; row[tid + 256] = x1 - L; row[tid + 512] = x2 - L; row[tid + 768] = x3 - L;
}

// ---------------------------------------------------------------------------
extern "C" void kernel_launch(void* const* d_in, const int* in_sizes, int n_in,
                              void* d_out, int out_size, void* d_ws, size_t ws_size,
                              hipStream_t stream)
{
    const int*   X  = (const int*)d_in[0];
    const float* Wi = (const float*)d_in[1];
    const float* bi = (const float*)d_in[2];
    const float* Wh = (const float*)d_in[3];
    const float* bh = (const float*)d_in[4];
    const float* Wl = (const float*)d_in[5];
    const float* bl = (const float*)d_in[6];
    float* out = (float*)d_out;

    char* p = (char*)d_ws;
    auto alloc = [&](size_t bytes) {
        char* r = p;
        p += (bytes + 255) & ~(size_t)255;
        return r;
    };
    u16*   WhTh  = (u16*)alloc((size_t)16384 * 1024 * 2);
    u16*   WhTl  = (u16*)alloc((size_t)16384 * 1024 * 2);
    u16*   WlTh  = (u16*)alloc((size_t)1024 * 1024 * 2);
    u16*   WlTl  = (u16*)alloc((size_t)1024 * 1024 * 2);
    float* gates = (float*)alloc((size_t)256 * 16384 * 4);
    float* c     = (float*)alloc((size_t)256 * 4096 * 4);
    u16*   hh    = (u16*)alloc((size_t)262144 * 2);
    u16*   hl    = (u16*)alloc((size_t)262144 * 2);
    float* bsum  = (float*)alloc((size_t)16384 * 4);

    transpose_split<<<dim3(256, 16), 256, 0, stream>>>(Wh, WhTh, WhTl, 16384);
    transpose_split<<<dim3(16, 16),  256, 0, stream>>>(Wl, WlTh, WlTl, 1024);
    init_state<<<4096, 256, 0, stream>>>(c, hh, hl, bsum, bi, bh);

    for (int t = 0; t < 128; ++t) {
        gemm3<0><<<512, 256, 0, stream>>>(hh, hl, WhTh, WhTl, gates, 16384, bsum, X, t, Wi);
        cell_update<<<1024, 256, 0, stream>>>(gates, c, hh, hl);
    }

    gemm3<1><<<32, 256, 0, stream>>>(hh, hl, WlTh, WlTl, out, 1024, bl, nullptr, 0, nullptr);
    logsoftmax_k<<<256, 256, 0, stream>>>(out);
}

// Round 2
// 5344.699 us; speedup vs baseline: 1.0158x; 1.0158x over previous
//
#include <hip/hip_runtime.h>
#include <hip/hip_bf16.h>

typedef unsigned short u16;
typedef unsigned int u32;
typedef __attribute__((ext_vector_type(8))) short short8;
typedef __attribute__((ext_vector_type(4))) float f32x4;

#define GLD_LDS(gptr, lptr) \
    __builtin_amdgcn_global_load_lds((const __attribute__((address_space(1))) void*)(gptr), \
                                     (__attribute__((address_space(3))) void*)(lptr), 16, 0, 0)

__device__ __forceinline__ u32 bf16_rne(float f) {
    u32 u = __float_as_uint(f);
    return (u + 0x7FFFu + ((u >> 16) & 1u)) >> 16;
}

// ---------------------------------------------------------------------------
// Transpose + split fp32 [1024][N] -> bf16 hi/lo [N][1024]
// ---------------------------------------------------------------------------
__global__ __launch_bounds__(256) void transpose_split(
    const float* __restrict__ W, u16* __restrict__ Thi, u16* __restrict__ Tlo, int N)
{
    __shared__ float tile[64][65];
    int n0 = blockIdx.x * 64;
    int k0 = blockIdx.y * 64;
    int tid = threadIdx.x;
    int tr = tid >> 4;      // 0..15
    int tc = tid & 15;      // 0..15
#pragma unroll
    for (int it = 0; it < 4; ++it) {
        int kr = it * 16 + tr;
        const float4* src = (const float4*)&W[(size_t)(k0 + kr) * N + n0 + tc * 4];
        float4 v = *src;
        tile[kr][tc * 4 + 0] = v.x;
        tile[kr][tc * 4 + 1] = v.y;
        tile[kr][tc * 4 + 2] = v.z;
        tile[kr][tc * 4 + 3] = v.w;
    }
    __syncthreads();
#pragma unroll
    for (int it = 0; it < 4; ++it) {
        int nr = it * 16 + tr;
        u32 h[4], l[4];
#pragma unroll
        for (int j = 0; j < 4; ++j) {
            float f = tile[tc * 4 + j][nr];
            u32 hi = bf16_rne(f);
            float hif = __uint_as_float(hi << 16);
            float lo = f - hif;
            h[j] = hi;
            l[j] = bf16_rne(lo);
        }
        size_t idx = (size_t)(n0 + nr) * 1024 + k0 + tc * 4;
        uint2 ph, pl;
        ph.x = h[0] | (h[1] << 16); ph.y = h[2] | (h[3] << 16);
        pl.x = l[0] | (l[1] << 16); pl.y = l[2] | (l[3] << 16);
        *(uint2*)&Thi[idx] = ph;
        *(uint2*)&Tlo[idx] = pl;
    }
}

// ---------------------------------------------------------------------------
// Init: zero c, zero h splits, bias_sum = bi + bh
// ---------------------------------------------------------------------------
__global__ __launch_bounds__(256) void init_state(
    float* __restrict__ c, u16* __restrict__ hh, u16* __restrict__ hl,
    float* __restrict__ bsum, const float* __restrict__ bi, const float* __restrict__ bh)
{
    int i = blockIdx.x * 256 + threadIdx.x;   // 0 .. 1048575
    c[i] = 0.0f;
    if (i < 262144) { hh[i] = 0; hl[i] = 0; }
    if (i < 16384)  bsum[i] = bi[i] + bh[i];
}

// ---------------------------------------------------------------------------
// Step 0: h == 0, so gates = bsum + Wi[X[b,0]]  (skips a full GEMM)
// ---------------------------------------------------------------------------
__global__ __launch_bounds__(256) void gates_step0(
    const float* __restrict__ bsum, const int* __restrict__ X,
    const float* __restrict__ Wi, float* __restrict__ gates)
{
    int gid = blockIdx.x * 256 + threadIdx.x;   // 0 .. 1048575 (256 * 4096 float4s)
    int b = gid >> 12;
    int c4 = (gid & 4095) * 4;
    int xr = X[b * 128];                         // t = 0
    float4 w = *(const float4*)&Wi[(size_t)xr * 16384 + c4];
    float4 bs = *(const float4*)&bsum[c4];
    float4 o;
    o.x = w.x + bs.x; o.y = w.y + bs.y; o.z = w.z + bs.z; o.w = w.w + bs.w;
    *(float4*)&gates[(size_t)b * 16384 + c4] = o;
}

// ---------------------------------------------------------------------------
// bf16x3 GEMM: C[256][N] = h(256x1024) @ W(1024xN) (+ bias [+ Wi[X[b,t]] gather])
// BM=128, BN=128, BK=32; 256 threads = 4 waves, each wave a 64x64 tile (4x4 acc).
// grid = 2 * (N/128) blocks. XCD-pair swizzle: the two m-halves of one n-tile
// land on the same XCD (bids b, b+8) so B's second read hits that XCD's L2.
// EPI==0: gates epilogue (bias_sum + Wi gather). EPI==1: logits (bias=bl).
// ---------------------------------------------------------------------------
template <int EPI>
__global__ __launch_bounds__(256) void gemm3(
    const u16* __restrict__ Ahi, const u16* __restrict__ Alo,
    const u16* __restrict__ Bhi, const u16* __restrict__ Blo,
    float* __restrict__ C, int N,
    const float* __restrict__ bias,
    const int* __restrict__ X, int t, const float* __restrict__ Wi)
{
    constexpr int KD = 1024;
    // LDS u16 regions per buf: AHI [0,4096) ALO [4096,8192) BHI [8192,12288) BLO [12288,16384)
    __shared__ u16 lds[2][16384];

    int bid = blockIdx.x;
    int xcd = bid & 7, g = bid >> 3;
    int m0 = (g & 1) * 128;
    int n0 = ((g >> 1) * 8 + xcd) * 128;
    int tid  = threadIdx.x;
    int lane = tid & 63;
    int wave = tid >> 6;
    int wm = wave >> 1, wn = wave & 1;
    int quad = lane >> 4, l15 = lane & 15;

    f32x4 acc[4][4] = {};

    auto stage = [&](int buf, int kc) {
        int k0 = kc * 32;
#pragma unroll
        for (int j = 0; j < 2; ++j) {
            int seg = j * 256 + tid;          // 0..511
            int row = seg >> 2, s = seg & 3;
            size_t ga = (size_t)(m0 + row) * KD + k0 + s * 8;
            GLD_LDS(Ahi + ga, &lds[buf][0    + seg * 8]);
            GLD_LDS(Alo + ga, &lds[buf][4096 + seg * 8]);
            size_t gb = (size_t)(n0 + row) * KD + k0 + s * 8;
            GLD_LDS(Bhi + gb, &lds[buf][8192  + seg * 8]);
            GLD_LDS(Blo + gb, &lds[buf][12288 + seg * 8]);
        }
    };

    stage(0, 0);
    constexpr int NK = KD / 32;  // 32 chunks
    for (int kc = 0; kc < NK; ++kc) {
        __syncthreads();
        if (kc + 1 < NK) stage((kc + 1) & 1, kc + 1);
        int buf = kc & 1;

        short8 afh[4], afl[4], bfh[4], bfl[4];
#pragma unroll
        for (int i = 0; i < 4; ++i) {
            int ar = wm * 64 + i * 16 + l15;
            afh[i] = *(const short8*)&lds[buf][0    + ar * 32 + quad * 8];
            afl[i] = *(const short8*)&lds[buf][4096 + ar * 32 + quad * 8];
            int br = wn * 64 + i * 16 + l15;
            bfh[i] = *(const short8*)&lds[buf][8192  + br * 32 + quad * 8];
            bfl[i] = *(const short8*)&lds[buf][12288 + br * 32 + quad * 8];
        }
#pragma unroll
        for (int mi = 0; mi < 4; ++mi)
#pragma unroll
            for (int ni = 0; ni < 4; ++ni) {
                acc[mi][ni] = __builtin_amdgcn_mfma_f32_16x16x32_bf16(afh[mi], bfh[ni], acc[mi][ni], 0, 0, 0);
                acc[mi][ni] = __builtin_amdgcn_mfma_f32_16x16x32_bf16(afh[mi], bfl[ni], acc[mi][ni], 0, 0, 0);
                acc[mi][ni] = __builtin_amdgcn_mfma_f32_16x16x32_bf16(afl[mi], bfh[ni], acc[mi][ni], 0, 0, 0);
            }
    }

    // Epilogue: C/D layout col = lane&15, row = quad*4 + r
#pragma unroll
    for (int mi = 0; mi < 4; ++mi) {
        int rbase = m0 + wm * 64 + mi * 16 + quad * 4;
#pragma unroll
        for (int ni = 0; ni < 4; ++ni) {
            int col = n0 + wn * 64 + ni * 16 + l15;
            float bv = bias[col];
#pragma unroll
            for (int r = 0; r < 4; ++r) {
                int row = rbase + r;
                float v = acc[mi][ni][r] + bv;
                if constexpr (EPI == 0) {
                    int xr = X[row * 128 + t];
                    v += Wi[(size_t)xr * 16384 + col];
                }
                C[(size_t)row * N + col] = v;
            }
        }
    }
}

// ---------------------------------------------------------------------------
// Cell update (float4): gates[256][16384] -> c, h (split to bf16 hi/lo)
// ---------------------------------------------------------------------------
__global__ __launch_bounds__(256) void cell_update(
    const float* __restrict__ gates, float* __restrict__ c,
    u16* __restrict__ hh, u16* __restrict__ hl)
{
    int gid = blockIdx.x * 256 + threadIdx.x;   // 0..65535
    int b = gid >> 8, h4 = (gid & 255) << 2;
    const float* gp = gates + (size_t)b * 16384 + h4;
    float* cp = c + (size_t)b * 4096 + h4;

    float best[4] = {-3.4e38f, -3.4e38f, -3.4e38f, -3.4e38f};
    float csel[4] = {0.f, 0.f, 0.f, 0.f};
#pragma unroll
    for (int kk = 0; kk < 4; ++kk) {
        float4 gi = *(const float4*)(gp + kk * 4096 + 0);
        float4 gf = *(const float4*)(gp + kk * 4096 + 1024);
        float4 gg = *(const float4*)(gp + kk * 4096 + 2048);
        float4 go = *(const float4*)(gp + kk * 4096 + 3072);
        float4 cc = *(const float4*)(cp + kk * 1024);
        float gia[4] = {gi.x, gi.y, gi.z, gi.w};
        float gfa[4] = {gf.x, gf.y, gf.z, gf.w};
        float gga[4] = {gg.x, gg.y, gg.z, gg.w};
        float goa[4] = {go.x, go.y, go.z, go.w};
        float cca[4] = {cc.x, cc.y, cc.z, cc.w};
        float cna[4];
#pragma unroll
        for (int j = 0; j < 4; ++j) {
            float ig = 1.0f / (1.0f + expf(-gia[j]));
            float fg = 1.0f / (1.0f + expf(-gfa[j]));
            float tg = tanhf(gga[j]);
            cna[j] = fg * cca[j] + ig * tg;
            if (goa[j] > best[j]) { best[j] = goa[j]; csel[j] = cna[j]; } // strict > = first-max
        }
        float4 cn = {cna[0], cna[1], cna[2], cna[3]};
        *(float4*)(cp + kk * 1024) = cn;
    }
    ushort4 vh, vl;
    u16* ph = (u16*)&vh; u16* pl = (u16*)&vl;
#pragma unroll
    for (int j = 0; j < 4; ++j) {
        float h = (1.0f / (1.0f + expf(-best[j]))) * tanhf(csel[j]);
        u32 hi = bf16_rne(h);
        float hif = __uint_as_float(hi << 16);
        u32 lo = bf16_rne(h - hif);
        ph[j] = (u16)hi;
        pl[j] = (u16)lo;
    }
    *(ushort4*)&hh[gid * 4] = vh;
    *(ushort4*)&hl[gid * 4] = vl;
}

// ---------------------------------------------------------------------------
// Row-wise log_softmax in place over [256][1024]
// ---------------------------------------------------------------------------
__global__ __launch_bounds__(256) void logsoftmax_k(float* __restrict__ io)
{
    int b = blockIdx.x;
    float* row = io + (size_t)b * 1024;
    int tid = threadIdx.x;
    float x0 = row[tid], x1 = row[tid + 256], x2 = row[tid + 512], x3 = row[tid + 768];
    float m = fmaxf(fmaxf(x0, x1), fmaxf(x2, x3));
#pragma unroll
    for (int off = 32; off > 0; off >>= 1) m = fmaxf(m, __shfl_down(m, off, 64));
    __shared__ float sm[4], ss[4];
    if ((tid & 63) == 0) sm[tid >> 6] = m;
    __syncthreads();
    float M = fmaxf(fmaxf(sm[0], sm[1]), fmaxf(sm[2], sm[3]));
    float s = expf(x0 - M) + expf(x1 - M) + expf(x2 - M) + expf(x3 - M);
#pragma unroll
    for (int off = 32; off > 0; off >>= 1) s += __shfl_down(s, off, 64);
    if ((tid & 63) == 0) ss[tid >> 6] = s;
    __syncthreads();
    float L = M + logf(ss[0] + ss[1] + ss[2] + ss[3]);
    row[tid] = x0 - L; row[tid + 256] = x1 - L; row[tid + 512] = x2 - L; row[tid + 768] = x3 - L;
}

// ---------------------------------------------------------------------------
extern "C" void kernel_launch(void* const* d_in, const int* in_sizes, int n_in,
                              void* d_out, int out_size, void* d_ws, size_t ws_size,
                              hipStream_t stream)
{
    const int*   X  = (const int*)d_in[0];
    const float* Wi = (const float*)d_in[1];
    const float* bi = (const float*)d_in[2];
    const float* Wh = (const float*)d_in[3];
    const float* bh = (const float*)d_in[4];
    const float* Wl = (const float*)d_in[5];
    const float* bl = (const float*)d_in[6];
    float* out = (float*)d_out;

    char* p = (char*)d_ws;
    auto alloc = [&](size_t bytes) {
        char* r = p;
        p += (bytes + 255) & ~(size_t)255;
        return r;
    };
    u16*   WhTh  = (u16*)alloc((size_t)16384 * 1024 * 2);
    u16*   WhTl  = (u16*)alloc((size_t)16384 * 1024 * 2);
    u16*   WlTh  = (u16*)alloc((size_t)1024 * 1024 * 2);
    u16*   WlTl  = (u16*)alloc((size_t)1024 * 1024 * 2);
    float* gates = (float*)alloc((size_t)256 * 16384 * 4);
    float* c     = (float*)alloc((size_t)256 * 4096 * 4);
    u16*   hh    = (u16*)alloc((size_t)262144 * 2);
    u16*   hl    = (u16*)alloc((size_t)262144 * 2);
    float* bsum  = (float*)alloc((size_t)16384 * 4);

    transpose_split<<<dim3(256, 16), 256, 0, stream>>>(Wh, WhTh, WhTl, 16384);
    transpose_split<<<dim3(16, 16),  256, 0, stream>>>(Wl, WlTh, WlTl, 1024);
    init_state<<<4096, 256, 0, stream>>>(c, hh, hl, bsum, bi, bh);

    // Step 0: h == 0, gates are just bsum + embedding gather
    gates_step0<<<4096, 256, 0, stream>>>(bsum, X, Wi, gates);
    cell_update<<<256, 256, 0, stream>>>(gates, c, hh, hl);

    for (int t = 1; t < 128; ++t) {
        gemm3<0><<<256, 256, 0, stream>>>(hh, hl, WhTh, WhTl, gates, 16384, bsum, X, t, Wi);
        cell_update<<<256, 256, 0, stream>>>(gates, c, hh, hl);
    }

    gemm3<1><<<16, 256, 0, stream>>>(hh, hl, WlTh, WlTl, out, 1024, bl, nullptr, 0, nullptr);
    logsoftmax_k<<<256, 256, 0, stream>>>(out);
}

// Round 3
// 4929.338 us; speedup vs baseline: 1.1013x; 1.0843x over previous
//
#include <hip/hip_runtime.h>
#include <hip/hip_bf16.h>

typedef unsigned short u16;
typedef unsigned int u32;
typedef __attribute__((ext_vector_type(8))) short short8;
typedef __attribute__((ext_vector_type(4))) float f32x4;

#define GLD_LDS(gptr, lptr) \
    __builtin_amdgcn_global_load_lds((const __attribute__((address_space(1))) void*)(gptr), \
                                     (__attribute__((address_space(3))) void*)(lptr), 16, 0, 0)

__device__ __forceinline__ u32 bf16_rne(float f) {
    u32 u = __float_as_uint(f);
    return (u + 0x7FFFu + ((u >> 16) & 1u)) >> 16;
}

// column permutation: orig col c = k*4096 + g*1024 + hx  ->  n = hx*16 + k*4 + g
__device__ __forceinline__ int permcol(int c) {
    return (c & 1023) * 16 + ((c >> 12) & 3) * 4 + ((c >> 10) & 3);
}

__device__ __forceinline__ float sigf(float x) { return 1.0f / (1.0f + expf(-x)); }

// ---------------------------------------------------------------------------
// Transpose + split fp32 [1024][N] -> bf16 hi/lo [N'][1024]; N' row = perm(col)
// ---------------------------------------------------------------------------
template <bool PERM>
__global__ __launch_bounds__(256) void transpose_split(
    const float* __restrict__ W, u16* __restrict__ Thi, u16* __restrict__ Tlo, int N)
{
    __shared__ float tile[64][65];
    int n0 = blockIdx.x * 64;
    int k0 = blockIdx.y * 64;
    int tid = threadIdx.x;
    int tr = tid >> 4;      // 0..15
    int tc = tid & 15;      // 0..15
#pragma unroll
    for (int it = 0; it < 4; ++it) {
        int kr = it * 16 + tr;
        const float4* src = (const float4*)&W[(size_t)(k0 + kr) * N + n0 + tc * 4];
        float4 v = *src;
        tile[kr][tc * 4 + 0] = v.x;
        tile[kr][tc * 4 + 1] = v.y;
        tile[kr][tc * 4 + 2] = v.z;
        tile[kr][tc * 4 + 3] = v.w;
    }
    __syncthreads();
#pragma unroll
    for (int it = 0; it < 4; ++it) {
        int nr = it * 16 + tr;
        u32 h[4], l[4];
#pragma unroll
        for (int j = 0; j < 4; ++j) {
            float f = tile[tc * 4 + j][nr];
            u32 hi = bf16_rne(f);
            float hif = __uint_as_float(hi << 16);
            float lo = f - hif;
            h[j] = hi;
            l[j] = bf16_rne(lo);
        }
        int ng = n0 + nr;
        int pr = PERM ? permcol(ng) : ng;
        size_t idx = (size_t)pr * 1024 + k0 + tc * 4;
        uint2 ph, pl;
        ph.x = h[0] | (h[1] << 16); ph.y = h[2] | (h[3] << 16);
        pl.x = l[0] | (l[1] << 16); pl.y = l[2] | (l[3] << 16);
        *(uint2*)&Thi[idx] = ph;
        *(uint2*)&Tlo[idx] = pl;
    }
}

// ---------------------------------------------------------------------------
// Permute Wi columns: WiP[r][n] = Wi[r][orig(n)]  (LDS-tiled, coalesced both sides)
// grid: dim3(4, 1024), 256 threads
// ---------------------------------------------------------------------------
__global__ __launch_bounds__(256) void permute_wi(
    const float* __restrict__ Wi, float* __restrict__ WiP)
{
    __shared__ float l[256 * 17];
    int r = blockIdx.y, hb = blockIdx.x, tid = threadIdx.x;
    const float* src = Wi + (size_t)r * 16384;
    float* dst = WiP + (size_t)r * 16384;
#pragma unroll
    for (int kg = 0; kg < 16; ++kg) {
        int k = kg >> 2, g = kg & 3;
        l[tid * 17 + kg] = src[k * 4096 + g * 1024 + hb * 256 + tid];
    }
    __syncthreads();
#pragma unroll
    for (int it = 0; it < 16; ++it) {
        int j = it * 256 + tid;
        dst[hb * 4096 + j] = l[(j >> 4) * 17 + (j & 15)];
    }
}

// ---------------------------------------------------------------------------
// Init: bsum = bi + bh (plain and permuted)
// ---------------------------------------------------------------------------
__global__ __launch_bounds__(256) void init_state(
    float* __restrict__ bsum, float* __restrict__ bsumP,
    const float* __restrict__ bi, const float* __restrict__ bh)
{
    int i = blockIdx.x * 256 + threadIdx.x;   // 0..16383
    float v = bi[i] + bh[i];
    bsum[i] = v;
    bsumP[permcol(i)] = v;
}

// ---------------------------------------------------------------------------
// Step 0: h == 0, c == 0  ->  gates = bsum + Wi[X[b,0]], cell update inline.
// c layout: c4[b][hx] = float4 over k.  Writes h split into (Ohi, Olo).
// ---------------------------------------------------------------------------
__global__ __launch_bounds__(256) void cell0(
    const float* __restrict__ bsum, const int* __restrict__ X,
    const float* __restrict__ Wi,
    float* __restrict__ c4, u16* __restrict__ Ohi, u16* __restrict__ Olo)
{
    int gid = blockIdx.x * 256 + threadIdx.x;   // 0..262143
    int b = gid >> 10, hx = gid & 1023;
    int xr = X[b * 128];
    const float* wr = Wi + (size_t)xr * 16384;
    float best = -3.4e38f, csel = 0.0f;
    float cn[4];
#pragma unroll
    for (int k = 0; k < 4; ++k) {
        int base = k * 4096 + hx;
        float gi = bsum[base + 0]    + wr[base + 0];
        float gf = bsum[base + 1024] + wr[base + 1024];
        float gg = bsum[base + 2048] + wr[base + 2048];
        float go = bsum[base + 3072] + wr[base + 3072];
        float ig = sigf(gi);
        float fg = sigf(gf); (void)fg;     // c_old = 0
        float tg = tanhf(gg);
        cn[k] = ig * tg;
        if (go > best) { best = go; csel = cn[k]; }
    }
    float4 cv = {cn[0], cn[1], cn[2], cn[3]};
    *(float4*)&c4[(size_t)gid * 4] = cv;
    float h = sigf(best) * tanhf(csel);
    u32 hi = bf16_rne(h);
    float hif = __uint_as_float(hi << 16);
    u32 lo = bf16_rne(h - hif);
    Ohi[gid] = (u16)hi;
    Olo[gid] = (u16)lo;
}

// ---------------------------------------------------------------------------
// Fused step: gates GEMM (bf16x3, permuted columns) + cell update.
// BM=128, BN=64, BK=32; 256 threads = 4 waves, wave tile 64x32 (4x2 acc).
// grid 512: xcd swizzle pairs the two m-halves of one n-tile on one XCD.
// Epilogue: acc + bsumP + WiP-gather -> LDS tile [128][66] -> cell math ->
// c4 update + h written split to (Ohi, Olo) [double-buffered vs (Ahi, Alo)].
// ---------------------------------------------------------------------------
__global__ __launch_bounds__(256) void fused_step(
    const u16* __restrict__ Ahi, const u16* __restrict__ Alo,
    const u16* __restrict__ Bhi, const u16* __restrict__ Blo,
    const float* __restrict__ bsumP, const float* __restrict__ WiP,
    const int* __restrict__ X, int t,
    float* __restrict__ c4, u16* __restrict__ Ohi, u16* __restrict__ Olo)
{
    constexpr int KD = 1024;
    // staging: 2 bufs x 12288 u16 (A hi [0,4096) lo [4096,8192), B hi [8192,10240) lo [10240,12288))
    __shared__ __align__(16) char smem[49152];
    u16* lds = (u16*)smem;
    float* tile = (float*)smem;   // epilogue reuse: [128][66] floats = 33 KB

    int bid = blockIdx.x;
    int xcd = bid & 7, rr = bid >> 3;           // rr 0..63
    int m0 = (rr & 1) * 128;
    int n0 = ((rr >> 1) * 8 + xcd) * 64;
    int tid  = threadIdx.x;
    int lane = tid & 63;
    int wave = tid >> 6;
    int wm = wave >> 1, wn = wave & 1;
    int quad = lane >> 4, l15 = lane & 15;

    f32x4 acc[4][2] = {};

    auto stage = [&](int buf, int kc) {
        int k0 = kc * 32;
        int base = buf * 12288;
#pragma unroll
        for (int j = 0; j < 2; ++j) {
            int seg = j * 256 + tid;          // 0..511
            int row = seg >> 2, s = seg & 3;
            size_t ga = (size_t)(m0 + row) * KD + k0 + s * 8;
            GLD_LDS(Ahi + ga, &lds[base + 0    + seg * 8]);
            GLD_LDS(Alo + ga, &lds[base + 4096 + seg * 8]);
        }
        {
            int row = tid >> 2, s = tid & 3;
            size_t gb = (size_t)(n0 + row) * KD + k0 + s * 8;
            GLD_LDS(Bhi + gb, &lds[base + 8192  + tid * 8]);
            GLD_LDS(Blo + gb, &lds[base + 10240 + tid * 8]);
        }
    };

    stage(0, 0);
    constexpr int NK = KD / 32;
    for (int kc = 0; kc < NK; ++kc) {
        __syncthreads();
        if (kc + 1 < NK) stage((kc + 1) & 1, kc + 1);
        int base = (kc & 1) * 12288;

        short8 afh[4], afl[4], bfh[2], bfl[2];
#pragma unroll
        for (int mi = 0; mi < 4; ++mi) {
            int ar = wm * 64 + mi * 16 + l15;
            afh[mi] = *(const short8*)&lds[base + 0    + ar * 32 + quad * 8];
            afl[mi] = *(const short8*)&lds[base + 4096 + ar * 32 + quad * 8];
        }
#pragma unroll
        for (int ni = 0; ni < 2; ++ni) {
            int br = wn * 32 + ni * 16 + l15;
            bfh[ni] = *(const short8*)&lds[base + 8192  + br * 32 + quad * 8];
            bfl[ni] = *(const short8*)&lds[base + 10240 + br * 32 + quad * 8];
        }
        // term-major: 8 independent MFMAs per burst; per-acc add order unchanged
#pragma unroll
        for (int mi = 0; mi < 4; ++mi)
#pragma unroll
            for (int ni = 0; ni < 2; ++ni)
                acc[mi][ni] = __builtin_amdgcn_mfma_f32_16x16x32_bf16(afh[mi], bfh[ni], acc[mi][ni], 0, 0, 0);
#pragma unroll
        for (int mi = 0; mi < 4; ++mi)
#pragma unroll
            for (int ni = 0; ni < 2; ++ni)
                acc[mi][ni] = __builtin_amdgcn_mfma_f32_16x16x32_bf16(afh[mi], bfl[ni], acc[mi][ni], 0, 0, 0);
#pragma unroll
        for (int mi = 0; mi < 4; ++mi)
#pragma unroll
            for (int ni = 0; ni < 2; ++ni)
                acc[mi][ni] = __builtin_amdgcn_mfma_f32_16x16x32_bf16(afl[mi], bfh[ni], acc[mi][ni], 0, 0, 0);
    }

    __syncthreads();   // staging LDS -> epilogue tile reuse

    // gates = acc + bsumP + WiP[X[b,t]]  written to LDS tile (local coords)
#pragma unroll
    for (int mi = 0; mi < 4; ++mi) {
        int rbl = wm * 64 + mi * 16 + quad * 4;
#pragma unroll
        for (int ni = 0; ni < 2; ++ni) {
            int cl = wn * 32 + ni * 16 + l15;
            int cg = n0 + cl;
            float bv = bsumP[cg];
#pragma unroll
            for (int r = 0; r < 4; ++r) {
                int rl = rbl + r;
                int xr = X[(m0 + rl) * 128 + t];
                tile[rl * 66 + cl] = acc[mi][ni][r] + bv + WiP[(size_t)xr * 16384 + cg];
            }
        }
    }
    __syncthreads();

    // cell update: thread -> (b = m0 + (tid&127), two hx slots)
    int bl = tid & 127;
    int bg = m0 + bl;
    int hp = (tid >> 7) * 2;
    int hxbase = n0 >> 4;
#pragma unroll
    for (int u = 0; u < 2; ++u) {
        int hxl = hp + u;                     // 0..3
        int hxg = hxbase + hxl;
        const float* g16 = &tile[bl * 66 + hxl * 16];
        float* cp = &c4[((size_t)bg * 1024 + hxg) * 4];
        float4 cc = *(const float4*)cp;
        float ca[4] = {cc.x, cc.y, cc.z, cc.w};
        float best = -3.4e38f, csel = 0.0f;
        float cn[4];
#pragma unroll
        for (int k = 0; k < 4; ++k) {
            float gi = g16[k * 4 + 0];
            float gf = g16[k * 4 + 1];
            float gg = g16[k * 4 + 2];
            float go = g16[k * 4 + 3];
            float ig = sigf(gi);
            float fg = sigf(gf);
            float tg = tanhf(gg);
            cn[k] = fg * ca[k] + ig * tg;
            if (go > best) { best = go; csel = cn[k]; }   // strict > = first max
        }
        float4 cv = {cn[0], cn[1], cn[2], cn[3]};
        *(float4*)cp = cv;
        float h = sigf(best) * tanhf(csel);
        u32 hi = bf16_rne(h);
        float hif = __uint_as_float(hi << 16);
        u32 lo = bf16_rne(h - hif);
        Ohi[(size_t)bg * 1024 + hxg] = (u16)hi;
        Olo[(size_t)bg * 1024 + hxg] = (u16)lo;
    }
}

// ---------------------------------------------------------------------------
// Logits GEMM (unpermuted): C[256][1024] = h @ Wl + bl.  BM=128,BN=128, grid 16.
// ---------------------------------------------------------------------------
__global__ __launch_bounds__(256) void gemm_logits(
    const u16* __restrict__ Ahi, const u16* __restrict__ Alo,
    const u16* __restrict__ Bhi, const u16* __restrict__ Blo,
    float* __restrict__ C, const float* __restrict__ bias)
{
    constexpr int KD = 1024;
    __shared__ u16 lds[2][16384];
    int bid = blockIdx.x;
    int xcd = bid & 7, g = bid >> 3;
    int m0 = g * 128;
    int n0 = xcd * 128;
    int tid  = threadIdx.x;
    int lane = tid & 63;
    int wave = tid >> 6;
    int wm = wave >> 1, wn = wave & 1;
    int quad = lane >> 4, l15 = lane & 15;

    f32x4 acc[4][4] = {};

    auto stage = [&](int buf, int kc) {
        int k0 = kc * 32;
#pragma unroll
        for (int j = 0; j < 2; ++j) {
            int seg = j * 256 + tid;
            int row = seg >> 2, s = seg & 3;
            size_t ga = (size_t)(m0 + row) * KD + k0 + s * 8;
            GLD_LDS(Ahi + ga, &lds[buf][0    + seg * 8]);
            GLD_LDS(Alo + ga, &lds[buf][4096 + seg * 8]);
            size_t gb = (size_t)(n0 + row) * KD + k0 + s * 8;
            GLD_LDS(Bhi + gb, &lds[buf][8192  + seg * 8]);
            GLD_LDS(Blo + gb, &lds[buf][12288 + seg * 8]);
        }
    };

    stage(0, 0);
    constexpr int NK = KD / 32;
    for (int kc = 0; kc < NK; ++kc) {
        __syncthreads();
        if (kc + 1 < NK) stage((kc + 1) & 1, kc + 1);
        int buf = kc & 1;
        short8 afh[4], afl[4], bfh[4], bfl[4];
#pragma unroll
        for (int i = 0; i < 4; ++i) {
            int ar = wm * 64 + i * 16 + l15;
            afh[i] = *(const short8*)&lds[buf][0    + ar * 32 + quad * 8];
            afl[i] = *(const short8*)&lds[buf][4096 + ar * 32 + quad * 8];
            int br = wn * 64 + i * 16 + l15;
            bfh[i] = *(const short8*)&lds[buf][8192  + br * 32 + quad * 8];
            bfl[i] = *(const short8*)&lds[buf][12288 + br * 32 + quad * 8];
        }
#pragma unroll
        for (int mi = 0; mi < 4; ++mi)
#pragma unroll
            for (int ni = 0; ni < 4; ++ni)
                acc[mi][ni] = __builtin_amdgcn_mfma_f32_16x16x32_bf16(afh[mi], bfh[ni], acc[mi][ni], 0, 0, 0);
#pragma unroll
        for (int mi = 0; mi < 4; ++mi)
#pragma unroll
            for (int ni = 0; ni < 4; ++ni)
                acc[mi][ni] = __builtin_amdgcn_mfma_f32_16x16x32_bf16(afh[mi], bfl[ni], acc[mi][ni], 0, 0, 0);
#pragma unroll
        for (int mi = 0; mi < 4; ++mi)
#pragma unroll
            for (int ni = 0; ni < 4; ++ni)
                acc[mi][ni] = __builtin_amdgcn_mfma_f32_16x16x32_bf16(afl[mi], bfh[ni], acc[mi][ni], 0, 0, 0);
    }

#pragma unroll
    for (int mi = 0; mi < 4; ++mi) {
        int rbase = m0 + wm * 64 + mi * 16 + quad * 4;
#pragma unroll
        for (int ni = 0; ni < 4; ++ni) {
            int col = n0 + wn * 64 + ni * 16 + l15;
            float bv = bias[col];
#pragma unroll
            for (int r = 0; r < 4; ++r)
                C[(size_t)(rbase + r) * 1024 + col] = acc[mi][ni][r] + bv;
        }
    }
}

// ---------------------------------------------------------------------------
// Row-wise log_softmax in place over [256][1024]
// ---------------------------------------------------------------------------
__global__ __launch_bounds__(256) void logsoftmax_k(float* __restrict__ io)
{
    int b = blockIdx.x;
    float* row = io + (size_t)b * 1024;
    int tid = threadIdx.x;
    float x0 = row[tid], x1 = row[tid + 256], x2 = row[tid + 512], x3 = row[tid + 768];
    float m = fmaxf(fmaxf(x0, x1), fmaxf(x2, x3));
#pragma unroll
    for (int off = 32; off > 0; off >>= 1) m = fmaxf(m, __shfl_down(m, off, 64));
    __shared__ float sm[4], ss[4];
    if ((tid & 63) == 0) sm[tid >> 6] = m;
    __syncthreads();
    float M = fmaxf(fmaxf(sm[0], sm[1]), fmaxf(sm[2], sm[3]));
    float s = expf(x0 - M) + expf(x1 - M) + expf(x2 - M) + expf(x3 - M);
#pragma unroll
    for (int off = 32; off > 0; off >>= 1) s += __shfl_down(s, off, 64);
    if ((tid & 63) == 0) ss[tid >> 6] = s;
    __syncthreads();
    float L = M + logf(ss[0] + ss[1] + ss[2] + ss[3]);
    row[tid] = x0 - L; row[tid + 256] = x1 - L; row[tid + 512] = x2 - L; row[tid + 768] = x3 - L;
}

// ---------------------------------------------------------------------------
extern "C" void kernel_launch(void* const* d_in, const int* in_sizes, int n_in,
                              void* d_out, int out_size, void* d_ws, size_t ws_size,
                              hipStream_t stream)
{
    const int*   X  = (const int*)d_in[0];
    const float* Wi = (const float*)d_in[1];
    const float* bi = (const float*)d_in[2];
    const float* Wh = (const float*)d_in[3];
    const float* bh = (const float*)d_in[4];
    const float* Wl = (const float*)d_in[5];
    const float* bl = (const float*)d_in[6];
    float* out = (float*)d_out;

    char* p = (char*)d_ws;
    auto alloc = [&](size_t bytes) {
        char* r = p;
        p += (bytes + 255) & ~(size_t)255;
        return r;
    };
    u16*   WhTh = (u16*)alloc((size_t)16384 * 1024 * 2);
    u16*   WhTl = (u16*)alloc((size_t)16384 * 1024 * 2);
    u16*   WlTh = (u16*)alloc((size_t)1024 * 1024 * 2);
    u16*   WlTl = (u16*)alloc((size_t)1024 * 1024 * 2);
    float* WiP  = (float*)alloc((size_t)1024 * 16384 * 4);
    float* c4   = (float*)alloc((size_t)256 * 1024 * 4 * 4);
    u16*   h0h  = (u16*)alloc((size_t)262144 * 2);
    u16*   h0l  = (u16*)alloc((size_t)262144 * 2);
    u16*   h1h  = (u16*)alloc((size_t)262144 * 2);
    u16*   h1l  = (u16*)alloc((size_t)262144 * 2);
    float* bsum  = (float*)alloc((size_t)16384 * 4);
    float* bsumP = (float*)alloc((size_t)16384 * 4);

    transpose_split<true><<<dim3(256, 16), 256, 0, stream>>>(Wh, WhTh, WhTl, 16384);
    transpose_split<false><<<dim3(16, 16), 256, 0, stream>>>(Wl, WlTh, WlTl, 1024);
    permute_wi<<<dim3(4, 1024), 256, 0, stream>>>(Wi, WiP);
    init_state<<<64, 256, 0, stream>>>(bsum, bsumP, bi, bh);

    // Step 0 (h=0, c=0): writes h buffer 1
    cell0<<<1024, 256, 0, stream>>>(bsum, X, Wi, c4, h1h, h1l);

    for (int t = 1; t < 128; ++t) {
        const u16* ih = (t & 1) ? h1h : h0h;
        const u16* il = (t & 1) ? h1l : h0l;
        u16* oh = (t & 1) ? h0h : h1h;
        u16* ol = (t & 1) ? h0l : h1l;
        fused_step<<<512, 256, 0, stream>>>(ih, il, WhTh, WhTl, bsumP, WiP, X, t, c4, oh, ol);
    }

    // t=127 wrote buffer 0
    gemm_logits<<<16, 256, 0, stream>>>(h0h, h0l, WlTh, WlTl, out, bl);
    logsoftmax_k<<<256, 256, 0, stream>>>(out);
}